// Round 8
// baseline (177.494 us; speedup 1.0000x reference)
//
#include <hip/hip_runtime.h>

#define IN_DIM 128
#define NCOL   256          // UV row: [U(128) | V(128)], bf16
#define WPITCH 72           // per-wave LDS tile pitch in bf16 (144 B)

typedef __bf16 bfx8 __attribute__((ext_vector_type(8)));
typedef __bf16 bfx4 __attribute__((ext_vector_type(4)));
typedef float  f32x4 __attribute__((ext_vector_type(4)));

// ---------------- pre-pass: Weff = bf16 fused layer-1 weight, [256][128] ----------------
// Weff[n][k] = (n<128) ? W1[n][k] : W1[n-128][128+k]
__global__ __launch_bounds__(256) void prep_w(
    const float* __restrict__ W1, __bf16* __restrict__ Weff)
{
    const int t   = threadIdx.x;
    const int n   = blockIdx.x * 32 + (t >> 3);   // 8 threads per row
    const int k0  = (t & 7) * 16;                 // 16 ch per thread
    const float* src = (n < 128) ? (W1 + n * 256 + k0) : (W1 + (n - 128) * 256 + 128 + k0);
    __bf16* dst = Weff + n * IN_DIM + k0;
#pragma unroll
    for (int k = 0; k < 16; k += 4) {
        float4 f = *(const float4*)(src + k);
        bfx4 b;
        b[0] = (__bf16)f.x; b[1] = (__bf16)f.y; b[2] = (__bf16)f.z; b[3] = (__bf16)f.w;
        *(bfx4*)(dst + k) = b;
    }
}

// ---------------- GEMM: UV = bf16( z @ Weff^T + [b1|0] ) ----------------
// M=100000, K=128, N=256. ONE WAVE PER BLOCK (64 thr), no barriers at all:
// wave owns a 32m x 64n tile; grid = (M/32) x 4 = 12500 independent waves.
// TLP (>=16 resident waves/CU) hides HBM latency instead of intra-block ILP.
// z-loads issue up-front; Weff fragments stream per-kk from L2.
// Epilogue: wave-private LDS transpose (wave-synchronous, no __syncthreads)
// -> dense 128 B-per-row global stores (R3's proven-best store path).
__global__ __launch_bounds__(64) void gemm_mfma(
    const float* __restrict__ z, const __bf16* __restrict__ Weff,
    const float* __restrict__ b1, __bf16* __restrict__ UV, int M)
{
    __shared__ __bf16 tile[32][WPITCH];   // 4.6 KB, private to the single wave

    const int lane = threadIdx.x;         // 0..63
    const int l15  = lane & 15;
    const int q    = lane >> 4;           // quad 0..3
    const int s    = blockIdx.x & 3;      // n-slice: [s*64, s*64+64)
    const int m0   = (blockIdx.x >> 2) * 32;   // M % 32 == 0
    const int n0   = s * 64;

    // --- z fragments first: 16 independent HBM float4 loads, all in flight ---
    bfx8 zfrag[2][4];
#pragma unroll
    for (int mt = 0; mt < 2; ++mt) {
#pragma unroll
        for (int kk = 0; kk < 4; ++kk) {
            const float* p = z + (size_t)(m0 + mt * 16 + l15) * IN_DIM + kk * 32 + q * 8;
            float4 f0 = *(const float4*)p;
            float4 f1 = *(const float4*)(p + 4);
            bfx8 a;
            a[0] = (__bf16)f0.x; a[1] = (__bf16)f0.y; a[2] = (__bf16)f0.z; a[3] = (__bf16)f0.w;
            a[4] = (__bf16)f1.x; a[5] = (__bf16)f1.y; a[6] = (__bf16)f1.z; a[7] = (__bf16)f1.w;
            zfrag[mt][kk] = a;
        }
    }

    // --- bias for this lane's columns n = n0+nt*16+l15 (V half -> 0) ---
    float bias[4];
#pragma unroll
    for (int nt = 0; nt < 4; ++nt) {
        const int n = n0 + nt * 16 + l15;
        bias[nt] = (n < 128) ? b1[n] : 0.f;
    }

    f32x4 acc[2][4];
#pragma unroll
    for (int mt = 0; mt < 2; ++mt)
#pragma unroll
        for (int nt = 0; nt < 4; ++nt)
            acc[mt][nt] = (f32x4){0.f, 0.f, 0.f, 0.f};

    // --- K loop: stream Weff fragments per kk (L2-hot), 8 MFMA per kk ---
#pragma unroll
    for (int kk = 0; kk < 4; ++kk) {
        bfx8 wfrag[4];
#pragma unroll
        for (int nt = 0; nt < 4; ++nt)
            wfrag[nt] = *(const bfx8*)(Weff + (n0 + nt * 16 + l15) * IN_DIM
                                       + kk * 32 + q * 8);
#pragma unroll
        for (int mt = 0; mt < 2; ++mt)
#pragma unroll
            for (int nt = 0; nt < 4; ++nt)
                acc[mt][nt] = __builtin_amdgcn_mfma_f32_16x16x32_bf16(
                    zfrag[mt][kk], wfrag[nt], acc[mt][nt], 0, 0, 0);
    }

    // --- epilogue: bias + cvt into wave-private LDS (D: col=l15->n, row=q*4+r->m) ---
#pragma unroll
    for (int mt = 0; mt < 2; ++mt)
#pragma unroll
        for (int nt = 0; nt < 4; ++nt) {
            const int col = nt * 16 + l15;
#pragma unroll
            for (int r = 0; r < 4; ++r)
                tile[mt * 16 + q * 4 + r][col] = (__bf16)(acc[mt][nt][r] + bias[nt]);
        }
    // wave-synchronous: no barrier needed; compiler inserts lgkmcnt waits.

    // --- dense stores: 4 insts x (8 rows x 128 B contiguous per row) ---
#pragma unroll
    for (int p = 0; p < 4; ++p) {
        const int row = p * 8 + (lane >> 3);
        const int c   = lane & 7;
        bfx8 v = *(const bfx8*)&tile[row][c * 8];
        *(bfx8*)(UV + (size_t)(m0 + row) * NCOL + n0 + c * 8) = v;
    }
}

// ---------------- per-edge MLP ----------------
// 16-lane group handles 8 edges (16 independent 16 B gathers in flight/thread).
// lane covers 8 hidden channels; b1 already folded into U.
__global__ __launch_bounds__(256) void edge_mlp(
    const __bf16* __restrict__ UV, const int* __restrict__ ei,
    const float* __restrict__ W2, const float* __restrict__ b2,
    float* __restrict__ out, int E)
{
    const int gt   = blockIdx.x * blockDim.x + threadIdx.x;
    const int lane = threadIdx.x & 15;
    const int g    = gt >> 4;
    const int e0   = g * 8;
    const int j0   = lane * 8;

    float ww[8];
    {
        float4 w0 = *(const float4*)(W2 + j0);
        float4 w1 = *(const float4*)(W2 + j0 + 4);
        ww[0] = w0.x; ww[1] = w0.y; ww[2] = w0.z; ww[3] = w0.w;
        ww[4] = w1.x; ww[5] = w1.y; ww[6] = w1.z; ww[7] = w1.w;
    }

    if (e0 >= E) return;   // E % 8 == 0

    const int4 sa = *(const int4*)(ei + e0);
    const int4 sb = *(const int4*)(ei + e0 + 4);
    const int4 da = *(const int4*)(ei + E + e0);
    const int4 db = *(const int4*)(ei + E + e0 + 4);
    const int sidx[8] = {sa.x, sa.y, sa.z, sa.w, sb.x, sb.y, sb.z, sb.w};
    const int didx[8] = {da.x, da.y, da.z, da.w, db.x, db.y, db.z, db.w};

    bfx8 u[8], v[8];
#pragma unroll
    for (int t = 0; t < 8; ++t) {
        u[t] = *(const bfx8*)(UV + (size_t)sidx[t] * NCOL + j0);
        v[t] = *(const bfx8*)(UV + (size_t)didx[t] * NCOL + 128 + j0);
    }

    float s[8];
#pragma unroll
    for (int t = 0; t < 8; ++t) {
        float acc = 0.f;
#pragma unroll
        for (int i = 0; i < 8; ++i)
            acc = fmaf(fmaxf((float)u[t][i] + (float)v[t][i], 0.f), ww[i], acc);
        s[t] = acc;
    }

#pragma unroll
    for (int d = 1; d < 16; d <<= 1)
#pragma unroll
        for (int t = 0; t < 8; ++t)
            s[t] += __shfl_xor(s[t], d);

    if (lane == 0) {
        const float bb = b2[0];
        float4 o0 = make_float4(s[0] + bb, s[1] + bb, s[2] + bb, s[3] + bb);
        float4 o1 = make_float4(s[4] + bb, s[5] + bb, s[6] + bb, s[7] + bb);
        *(float4*)(out + e0)     = o0;
        *(float4*)(out + e0 + 4) = o1;
    }
}

extern "C" void kernel_launch(void* const* d_in, const int* in_sizes, int n_in,
                              void* d_out, int out_size, void* d_ws, size_t ws_size,
                              hipStream_t stream)
{
    const float* z  = (const float*)d_in[0];
    const int*   ei = (const int*)d_in[1];
    const float* W1 = (const float*)d_in[2];
    const float* b1 = (const float*)d_in[3];
    const float* W2 = (const float*)d_in[4];
    const float* b2 = (const float*)d_in[5];
    float* out = (float*)d_out;

    const int M = in_sizes[0] / IN_DIM;   // 100000 nodes
    const int E = in_sizes[1] / 2;        // 600000 edges

    __bf16* UV   = (__bf16*)d_ws;                 // [M][256] bf16 = 51.2 MB
    __bf16* Weff = UV + (size_t)M * NCOL;         // [256][128] bf16 = 64 KB

    prep_w<<<8, 256, 0, stream>>>(W1, Weff);

    const int gblocks = (M / 32) * 4;             // 12500 single-wave blocks
    gemm_mfma<<<gblocks, 64, 0, stream>>>(z, Weff, b1, UV, M);

    const int groups  = (E + 7) / 8;                  // 75000
    const int eblocks = (groups * 16 + 255) / 256;    // 4688
    edge_mlp<<<eblocks, 256, 0, stream>>>(UV, ei, W2, b2, out, E);
}